// Round 6
// baseline (95.292 us; speedup 1.0000x reference)
//
#include <hip/hip_runtime.h>

// ---------- constants (problem is fixed-shape) ----------
#define BB   16
#define PP   256
#define BP   4096        // B*P
#define DMODEL 1024
#define VV   1000
#define DLLM 4096
#define HH   16
#define DK   64
#define HDK  1024        // H*DK

using f32x4 = __attribute__((ext_vector_type(4))) float;
using s16x8 = __attribute__((ext_vector_type(8))) short;

__device__ __forceinline__ unsigned short f2bf(float f) {
    unsigned int u = __builtin_bit_cast(unsigned int, f);
    u = (u + 0x7FFFu + ((u >> 16) & 1u)) >> 16;   // RNE
    return (unsigned short)u;
}

__device__ __forceinline__ void gload_lds16(const unsigned short* g, unsigned short* lds) {
    __builtin_amdgcn_global_load_lds(
        (const __attribute__((address_space(1))) void*)g,
        (__attribute__((address_space(3))) void*)lds,
        16, 0, 0);
}

// ---------- MEGA1: colsum_partial ∪ cast_bf16 ∪ transpose(Wq) ∪ transpose(Wo) ----------
__device__ __forceinline__ void transpose_body(const float* __restrict__ src,
                                               unsigned short* __restrict__ dst,
                                               int R, int C, int bx, int by, int t,
                                               float (*tile)[33]) {
    int tx = t & 31, ty = t >> 5;                   // 32 x 8
    int c0 = bx * 32, r0 = by * 32;
#pragma unroll
    for (int j = 0; j < 4; ++j)
        tile[ty + j * 8][tx] = src[(size_t)(r0 + ty + j * 8) * C + c0 + tx];
    __syncthreads();
#pragma unroll
    for (int j = 0; j < 4; ++j)
        dst[(size_t)(c0 + ty + j * 8) * R + r0 + tx] = f2bf(tile[tx][ty + j * 8]);
}

__global__ void mega1(const float* __restrict__ src0, const float* __restrict__ src1,
                      float* __restrict__ part1,
                      const float* __restrict__ target, unsigned short* __restrict__ tgt_bf,
                      const float* __restrict__ Wq, unsigned short* __restrict__ wq_t,
                      const float* __restrict__ Wo, unsigned short* __restrict__ wo_t) {
    __shared__ float tile[32][33];
    int b = blockIdx.x, t = threadIdx.x;
    if (b < 1280) {
        int x = b & 15, y = (b >> 4) % 40, z = b / 640;
        int col = x * 256 + t;
        const float* src = z ? src1 : src0;
        int r0 = y * 25;
        float acc = 0.f;
        for (int r = 0; r < 25; ++r)
            acc += src[(size_t)(r0 + r) * DLLM + col];
        part1[((z * 40 + y) * DLLM) + col] = acc;
    } else if (b < 1280 + 4096) {
        int idx = (b - 1280) * 256 + t;
        float4 v = reinterpret_cast<const float4*>(target)[idx];
        ushort4 o = make_ushort4(f2bf(v.x), f2bf(v.y), f2bf(v.z), f2bf(v.w));
        reinterpret_cast<ushort4*>(tgt_bf)[idx] = o;
    } else if (b < 1280 + 4096 + 1024) {
        int b2 = b - 5376;
        transpose_body(Wq, wq_t, DMODEL, HDK, b2 & 31, b2 >> 5, t, tile);
    } else {
        int b2 = b - 6400;
        transpose_body(Wo, wo_t, HDK, DLLM, b2 & 127, b2 >> 7, t, tile);
    }
}

// ---------- gemv_partial2 (inlines colsum_reduce) ----------
__global__ void gemv_partial2(const float* __restrict__ Wk, const float* __restrict__ Wv,
                              const float* __restrict__ part1, float* __restrict__ part2) {
    __shared__ float vec[64];
    int c     = blockIdx.x * 256 + threadIdx.x;
    int chunk = blockIdx.y;
    int z     = blockIdx.z;
    const float* W = z ? Wv : Wk;
    if (threadIdx.x < 64) {
        int r = chunk * 64 + threadIdx.x;
        float a = 0.f;
        for (int p = 0; p < 40; ++p)
            a += part1[(size_t)(z * 40 + p) * DLLM + r];
        vec[threadIdx.x] = a;
    }
    __syncthreads();
    float acc = 0.f;
    int r0 = chunk * 64;
    for (int r = 0; r < 64; ++r)
        acc += vec[r] * W[(size_t)(r0 + r) * HDK + c];
    part2[((z * 64 + chunk) * HDK) + c] = acc;
}

__global__ void gemv_reduce(const float* __restrict__ part,
                            const float* __restrict__ bk, const float* __restrict__ bv,
                            float* __restrict__ kvsum) {
    int idx = blockIdx.x * 256 + threadIdx.x;
    int z = idx >> 10, c = idx & 1023;
    float acc = 0.f;
    for (int ch = 0; ch < 64; ++ch) acc += part[(size_t)(z * 64 + ch) * HDK + c];
    acc += (float)VV * (z ? bv[c] : bk[c]);
    kvsum[idx] = acc;
}

// ---------- m201-style 4-phase GEMM: C = A(MxK bf16) * Bt(NxK bf16)^T ----------
// BK=64, 2 LDS dbufs. Per K-tile: 4 phases of {<=12 ds_read | 1 half-tile
// stage (2 gload_lds) | barrier | setprio(1) 16-MFMA setprio(0) | barrier}.
// Quadrant order (m0-3,n0-1),(m4-7,n0-1),(m4-7,n2-3),(m0-3,n2-3): each LDS
// region read in exactly one early phase -> tile t+2 stages into the live
// buffer's dead regions (P2:A-Q0, P3:A-Q1, P4:B-H1), t+1's B-H2 at P1.
// vmcnt(6) once per tile (3 half-tiles in flight), never 0 in steady state.
// LDS swizzle: phys slot = logical slot ^ (row&7) (involution, both sides).
template<int EPI, int BMt, int BNt, int WM, int WN>
__global__ __launch_bounds__(WM * WN * 64, 2)
void gemm_p4(const unsigned short* __restrict__ A, const unsigned short* __restrict__ Bt,
             float* __restrict__ C, const float* __restrict__ bias,
             const float* __restrict__ kvsum, unsigned short* __restrict__ R,
             int N, int K, int gx) {
    constexpr int WAVES = WM * WN;
    constexpr int Mw = BMt / WM;           // per-wave output rows
    constexpr int M_REP = Mw / 16;         // 8 (gemm2) or 4 (gemm1)
    constexpr int M2 = M_REP / 2;
    static_assert(BNt / WN == 64, "wave col span must be 64");

    __shared__ __align__(16) unsigned short Asm[2][BMt * 64];
    __shared__ __align__(16) unsigned short Bsm[2][BNt * 64];

    // bijective XCD swizzle (grid % 8 == 0)
    const int nwg = gridDim.x, q8 = nwg >> 3;
    const int nb = (blockIdx.x & 7) * q8 + (blockIdx.x >> 3);
    const int bm = (nb / gx) * BMt;
    const int bn = (nb % gx) * BNt;

    const int t = threadIdx.x;
    const int w = t >> 6, lane = t & 63;
    const int wr = w / WN, wc = w % WN;
    const int l15 = lane & 15, kgrp = lane >> 4;

    // stage source col pre-swizzle: lane covers row +(lane>>3), phys slot lane&7;
    // content for phys slot s at local row r (r&7 == lane>>3) = (s^(r&7))*8.
    const int scol = ((lane & 7) ^ (lane >> 3)) * 8;
    const int srow = lane >> 3;

    // ds_read swizzled slot offsets (row&7 == l15&7 for all frags)
    const int so0 = ((kgrp ^ (lane & 7)) * 8);
    const int so1 = so0 ^ 32;               // slot^4
    const int rbA = (wr * Mw + l15) * 64;
    const int rbB = (wc * 64 + l15) * 64;

    f32x4 acc[M_REP][4] = {};

    auto stageA = [&](int qq, int tt, int bb) {
#pragma unroll
        for (int i = 0; i < 2; ++i) {
            int rb = i * (BMt / 2) + qq * (BMt / 4) + w * 8;
            gload_lds16(A + (size_t)(bm + rb + srow) * K + tt * 64 + scol,
                        &Asm[bb][rb * 64]);
        }
    };
    auto stageB = [&](int hh, int tt, int bb) {
#pragma unroll
        for (int i = 0; i < 2; ++i) {
            int p = i * (BNt / 128) + (w >> 2);
            int rb = p * 64 + hh * 32 + (w & 3) * 8;
            gload_lds16(Bt + (size_t)(bn + rb + srow) * K + tt * 64 + scol,
                        &Bsm[bb][rb * 64]);
        }
    };

    const int nT = K >> 6;
    // prologue: tile0 complete + tile1 all-but-B-H2 (guide: vmcnt(4), +3, vmcnt(6))
    stageA(0, 0, 0); stageA(1, 0, 0); stageB(0, 0, 0); stageB(1, 0, 0);
    asm volatile("s_waitcnt vmcnt(4)" ::: "memory");
    stageA(0, 1, 1); stageA(1, 1, 1); stageB(0, 1, 1);
    asm volatile("s_waitcnt vmcnt(6)" ::: "memory");
    __builtin_amdgcn_s_barrier();

    for (int tk = 0; tk < nT; ++tk) {
        const int b = tk & 1, ob = b ^ 1;
        s16x8 af0[M2][2], af1[M2][2], bf0[2][2], bf1[2][2];
        // ---- P1: read A-Q0 + B-H1; stage B-H2(t+1); MFMA m0-3 x n0-1 ----
#pragma unroll
        for (int m = 0; m < M2; ++m) {
            af0[m][0] = *reinterpret_cast<const s16x8*>(&Asm[b][rbA + m * 1024 + so0]);
            af0[m][1] = *reinterpret_cast<const s16x8*>(&Asm[b][rbA + m * 1024 + so1]);
        }
#pragma unroll
        for (int n = 0; n < 2; ++n) {
            bf0[n][0] = *reinterpret_cast<const s16x8*>(&Bsm[b][rbB + n * 1024 + so0]);
            bf0[n][1] = *reinterpret_cast<const s16x8*>(&Bsm[b][rbB + n * 1024 + so1]);
        }
        if (tk + 1 < nT) stageB(1, tk + 1, ob);
        __builtin_amdgcn_s_barrier();
        __builtin_amdgcn_s_setprio(1);
#pragma unroll
        for (int m = 0; m < M2; ++m)
#pragma unroll
            for (int n = 0; n < 2; ++n)
#pragma unroll
                for (int kk = 0; kk < 2; ++kk)
                    acc[m][n] = __builtin_amdgcn_mfma_f32_16x16x32_bf16(af0[m][kk], bf0[n][kk], acc[m][n], 0, 0, 0);
        __builtin_amdgcn_s_setprio(0);
        __builtin_amdgcn_s_barrier();
        // ---- P2: read A-Q1; stage A-Q0(t+2); MFMA m4-7 x n0-1 ----
#pragma unroll
        for (int m = 0; m < M2; ++m) {
            af1[m][0] = *reinterpret_cast<const s16x8*>(&Asm[b][rbA + (M2 + m) * 1024 + so0]);
            af1[m][1] = *reinterpret_cast<const s16x8*>(&Asm[b][rbA + (M2 + m) * 1024 + so1]);
        }
        if (tk + 2 < nT) stageA(0, tk + 2, b);
        if (tk == nT - 1) asm volatile("s_waitcnt vmcnt(0)" ::: "memory");
        __builtin_amdgcn_s_barrier();
        __builtin_amdgcn_s_setprio(1);
#pragma unroll
        for (int m = 0; m < M2; ++m)
#pragma unroll
            for (int n = 0; n < 2; ++n)
#pragma unroll
                for (int kk = 0; kk < 2; ++kk)
                    acc[M2 + m][n] = __builtin_amdgcn_mfma_f32_16x16x32_bf16(af1[m][kk], bf0[n][kk], acc[M2 + m][n], 0, 0, 0);
        __builtin_amdgcn_s_setprio(0);
        __builtin_amdgcn_s_barrier();
        // ---- P3: read B-H2; stage A-Q1(t+2); MFMA m4-7 x n2-3 ----
#pragma unroll
        for (int n = 0; n < 2; ++n) {
            bf1[n][0] = *reinterpret_cast<const s16x8*>(&Bsm[b][rbB + (2 + n) * 1024 + so0]);
            bf1[n][1] = *reinterpret_cast<const s16x8*>(&Bsm[b][rbB + (2 + n) * 1024 + so1]);
        }
        if (tk + 2 < nT) stageA(1, tk + 2, b);
        __builtin_amdgcn_s_barrier();
        __builtin_amdgcn_s_setprio(1);
#pragma unroll
        for (int m = 0; m < M2; ++m)
#pragma unroll
            for (int n = 0; n < 2; ++n)
#pragma unroll
                for (int kk = 0; kk < 2; ++kk)
                    acc[M2 + m][2 + n] = __builtin_amdgcn_mfma_f32_16x16x32_bf16(af1[m][kk], bf1[n][kk], acc[M2 + m][2 + n], 0, 0, 0);
        __builtin_amdgcn_s_setprio(0);
        __builtin_amdgcn_s_barrier();
        // ---- P4: no reads (af0 retained); stage B-H1(t+2); vmcnt; MFMA m0-3 x n2-3 ----
        if (tk + 2 < nT) stageB(0, tk + 2, b);
        if (tk + 2 < nT)      asm volatile("s_waitcnt vmcnt(6)" ::: "memory");
        else if (tk + 1 < nT) asm volatile("s_waitcnt vmcnt(2)" ::: "memory");
        __builtin_amdgcn_s_barrier();
        __builtin_amdgcn_s_setprio(1);
#pragma unroll
        for (int m = 0; m < M2; ++m)
#pragma unroll
            for (int n = 0; n < 2; ++n)
#pragma unroll
                for (int kk = 0; kk < 2; ++kk)
                    acc[m][2 + n] = __builtin_amdgcn_mfma_f32_16x16x32_bf16(af0[m][kk], bf1[n][kk], acc[m][2 + n], 0, 0, 0);
        __builtin_amdgcn_s_setprio(0);
        __builtin_amdgcn_s_barrier();
    }

    // epilogue: C/D layout col = lane&15, row = (lane>>4)*4 + j
    if (EPI == 0) {
#pragma unroll
        for (int m = 0; m < M_REP; ++m) {
            int grow = bm + wr * Mw + m * 16 + kgrp * 4;
#pragma unroll
            for (int n = 0; n < 4; ++n) {
                int gcol = bn + wc * 64 + n * 16 + l15;
                float bb = bias[gcol];
#pragma unroll
                for (int j = 0; j < 4; ++j)
                    C[(size_t)(grow + j) * N + gcol] = acc[m][n][j] + bb;
            }
        }
    } else {
        // wave's 64-col span = one head: softmax over head dim, scale by Vsum
        float bqv[4], ksv[4], vsv[4];
#pragma unroll
        for (int n = 0; n < 4; ++n) {
            int col = bn + wc * 64 + n * 16 + l15;
            bqv[n] = bias[col];
            ksv[n] = kvsum[col];
            vsv[n] = kvsum[HDK + col];
        }
#pragma unroll
        for (int m = 0; m < M_REP; ++m) {
            int grow = bm + wr * Mw + m * 16 + kgrp * 4;
#pragma unroll
            for (int j = 0; j < 4; ++j) {
                float x[4];
#pragma unroll
                for (int n = 0; n < 4; ++n)
                    x[n] = 0.125f * (acc[m][n][j] + bqv[n]) * ksv[n];
                float mx = fmaxf(fmaxf(x[0], x[1]), fmaxf(x[2], x[3]));
#pragma unroll
                for (int off = 8; off; off >>= 1) mx = fmaxf(mx, __shfl_xor(mx, off));
                float e[4], s = 0.f;
#pragma unroll
                for (int n = 0; n < 4; ++n) { e[n] = __expf(x[n] - mx); s += e[n]; }
#pragma unroll
                for (int off = 8; off; off >>= 1) s += __shfl_xor(s, off);
                float inv = 1.0f / s;
#pragma unroll
                for (int n = 0; n < 4; ++n) {
                    int col = bn + wc * 64 + n * 16 + l15;
                    R[(size_t)(grow + j) * N + col] = f2bf(e[n] * inv * vsv[n]);
                }
            }
        }
    }
}

// ---------- host launch ----------
extern "C" void kernel_launch(void* const* d_in, const int* in_sizes, int n_in,
                              void* d_out, int out_size, void* d_ws, size_t ws_size,
                              hipStream_t stream) {
    const float* target = (const float*)d_in[0];
    const float* source = (const float*)d_in[1];
    const float* value  = (const float*)d_in[2];
    const float* Wq = (const float*)d_in[3];
    const float* bq = (const float*)d_in[4];
    const float* Wk = (const float*)d_in[5];
    const float* bk = (const float*)d_in[6];
    const float* Wv = (const float*)d_in[7];
    const float* bv = (const float*)d_in[8];
    const float* Wo = (const float*)d_in[9];
    const float* bo = (const float*)d_in[10];
    float* out = (float*)d_out;

    char* ws = (char*)d_ws;
    float*          part1  = (float*)(ws);                      // 1.25MB
    float*          part2  = (float*)(ws + 0x180000);           // 512KB
    float*          kvsum  = (float*)(ws + 0x210000);           // 8KB
    unsigned short* tgt_bf = (unsigned short*)(ws + 0x400000);  // 8MB
    unsigned short* wq_t   = (unsigned short*)(ws + 0xC00000);  // 2MB
    unsigned short* wo_t   = (unsigned short*)(ws + 0xE00000);  // 8MB
    unsigned short* Rb     = (unsigned short*)(ws + 0x1600000); // 8MB

    // 1) fused prep: colsum partials + cast(target) + transpose(Wq) + transpose(Wo)
    mega1<<<10496, 256, 0, stream>>>(source, value, part1, target, tgt_bf, Wq, wq_t, Wo, wo_t);

    // 2) Ksum/Vsum GEMV + bias fold
    gemv_partial2<<<dim3(4, 64, 2), 256, 0, stream>>>(Wk, Wv, part1, part2);
    gemv_reduce<<<8, 256, 0, stream>>>(part2, bk, bv, kvsum);

    // 3) fused: S = target @ Wq; R = softmax_head(0.125*(S+bq)*Ksum) * Vsum (bf16)
    gemm_p4<1, 128, 128, 2, 2><<<256, 256, 0, stream>>>(
        tgt_bf, wq_t, nullptr, bq, kvsum, Rb, HDK, DMODEL, HDK / 128);

    // 4) out = R @ Wo + bo  (256² 4-phase m201-style schedule)
    gemm_p4<0, 256, 256, 2, 4><<<256, 512, 0, stream>>>(
        Rb, wo_t, out, bo, nullptr, nullptr, DLLM, HDK, DLLM / 256);
}

// Round 7
// 92.537 us; speedup vs baseline: 1.0298x; 1.0298x over previous
//
#include <hip/hip_runtime.h>

// ---------- constants (problem is fixed-shape) ----------
#define BB   16
#define PP   256
#define BP   4096        // B*P
#define DMODEL 1024
#define VV   1000
#define DLLM 4096
#define HH   16
#define DK   64
#define HDK  1024        // H*DK

using f32x4 = __attribute__((ext_vector_type(4))) float;
using s16x8 = __attribute__((ext_vector_type(8))) short;

__device__ __forceinline__ unsigned short f2bf(float f) {
    unsigned int u = __builtin_bit_cast(unsigned int, f);
    u = (u + 0x7FFFu + ((u >> 16) & 1u)) >> 16;   // RNE
    return (unsigned short)u;
}

__device__ __forceinline__ void gload_lds16(const unsigned short* g, unsigned short* lds) {
    __builtin_amdgcn_global_load_lds(
        (const __attribute__((address_space(1))) void*)g,
        (__attribute__((address_space(3))) void*)lds,
        16, 0, 0);
}

// ---------- MEGA1: colsum_partial ∪ cast_bf16 ∪ transpose(Wq) ∪ transpose(Wo) ----------
__device__ __forceinline__ void transpose_body(const float* __restrict__ src,
                                               unsigned short* __restrict__ dst,
                                               int R, int C, int bx, int by, int t,
                                               float (*tile)[33]) {
    int tx = t & 31, ty = t >> 5;                   // 32 x 8
    int c0 = bx * 32, r0 = by * 32;
#pragma unroll
    for (int j = 0; j < 4; ++j)
        tile[ty + j * 8][tx] = src[(size_t)(r0 + ty + j * 8) * C + c0 + tx];
    __syncthreads();
#pragma unroll
    for (int j = 0; j < 4; ++j)
        dst[(size_t)(c0 + ty + j * 8) * R + r0 + tx] = f2bf(tile[tx][ty + j * 8]);
}

__global__ void mega1(const float* __restrict__ src0, const float* __restrict__ src1,
                      float* __restrict__ part1,
                      const float* __restrict__ target, unsigned short* __restrict__ tgt_bf,
                      const float* __restrict__ Wq, unsigned short* __restrict__ wq_t,
                      const float* __restrict__ Wo, unsigned short* __restrict__ wo_t) {
    __shared__ float tile[32][33];
    int b = blockIdx.x, t = threadIdx.x;
    if (b < 1280) {
        int x = b & 15, y = (b >> 4) % 40, z = b / 640;
        int col = x * 256 + t;
        const float* src = z ? src1 : src0;
        int r0 = y * 25;
        float acc = 0.f;
        for (int r = 0; r < 25; ++r)
            acc += src[(size_t)(r0 + r) * DLLM + col];
        part1[((z * 40 + y) * DLLM) + col] = acc;
    } else if (b < 1280 + 4096) {
        int idx = (b - 1280) * 256 + t;
        float4 v = reinterpret_cast<const float4*>(target)[idx];
        ushort4 o = make_ushort4(f2bf(v.x), f2bf(v.y), f2bf(v.z), f2bf(v.w));
        reinterpret_cast<ushort4*>(tgt_bf)[idx] = o;
    } else if (b < 1280 + 4096 + 1024) {
        int b2 = b - 5376;
        transpose_body(Wq, wq_t, DMODEL, HDK, b2 & 31, b2 >> 5, t, tile);
    } else {
        int b2 = b - 6400;
        transpose_body(Wo, wo_t, HDK, DLLM, b2 & 127, b2 >> 7, t, tile);
    }
}

// ---------- gemv_partial2 (inlines colsum_reduce) ----------
__global__ void gemv_partial2(const float* __restrict__ Wk, const float* __restrict__ Wv,
                              const float* __restrict__ part1, float* __restrict__ part2) {
    __shared__ float vec[64];
    int c     = blockIdx.x * 256 + threadIdx.x;
    int chunk = blockIdx.y;
    int z     = blockIdx.z;
    const float* W = z ? Wv : Wk;
    if (threadIdx.x < 64) {
        int r = chunk * 64 + threadIdx.x;
        float a = 0.f;
        for (int p = 0; p < 40; ++p)
            a += part1[(size_t)(z * 40 + p) * DLLM + r];
        vec[threadIdx.x] = a;
    }
    __syncthreads();
    float acc = 0.f;
    int r0 = chunk * 64;
    for (int r = 0; r < 64; ++r)
        acc += vec[r] * W[(size_t)(r0 + r) * HDK + c];
    part2[((z * 64 + chunk) * HDK) + c] = acc;
}

__global__ void gemv_reduce(const float* __restrict__ part,
                            const float* __restrict__ bk, const float* __restrict__ bv,
                            float* __restrict__ kvsum) {
    int idx = blockIdx.x * 256 + threadIdx.x;
    int z = idx >> 10, c = idx & 1023;
    float acc = 0.f;
    for (int ch = 0; ch < 64; ++ch) acc += part[(size_t)(z * 64 + ch) * HDK + c];
    acc += (float)VV * (z ? bv[c] : bk[c]);
    kvsum[idx] = acc;
}

// ---------- counted-vmcnt GEMM, 3-buffer BK=32, distance-2 prefetch ----------
// Geometry chosen for 2 independent blocks/CU (un-synchronized barrier
// domains): one block's MFMA clusters overlap the other's ds_reads/staging.
// LDS swizzle: phys 16B-slot = logical ^ (super-row & 7); applied to the
// GLOBAL source address at staging (LDS dest linear for global_load_lds)
// and to the ds_read address (involution both sides; r4/r5: 0 conflicts).
// EPI=0: C(f32)=A*B^T+bias. EPI=1: fused per-head softmax -> bf16 R.
template<int EPI, int BMt, int BNt, int WM, int WN>
__global__ __launch_bounds__(WM * WN * 64, 2)
void gemm_ctd3(const unsigned short* __restrict__ A, const unsigned short* __restrict__ Bt,
               float* __restrict__ C, const float* __restrict__ bias,
               const float* __restrict__ kvsum, unsigned short* __restrict__ R,
               int N, int K, int gx) {
    constexpr int WAVES = WM * WN;
    constexpr int Mw = BMt / WM;
    constexpr int M_REP = Mw / 16;
    constexpr int NA = BMt * 32 / (WAVES * 512);   // A gloads per thread per stage
    constexpr int NB = BNt * 32 / (WAVES * 512);   // B gloads per thread per stage
    constexpr int NST = NA + NB;                    // vm-ops in flight per staged tile
    static_assert(BNt / WN == 64, "wave col span must be 64");
    static_assert(NA >= 1 && NB >= 1, "staging geometry");

    __shared__ __align__(16) unsigned short Asm[3][BMt * 32];
    __shared__ __align__(16) unsigned short Bsm[3][BNt * 32];

    // bijective XCD swizzle (grid % 8 == 0)
    const int nwg = gridDim.x, q8 = nwg >> 3;
    const int nb = (blockIdx.x & 7) * q8 + (blockIdx.x >> 3);
    const int bm = (nb / gx) * BMt;
    const int bn = (nb % gx) * BNt;

    const int t = threadIdx.x;
    const int w = t >> 6, lane = t & 63;
    const int wr = w / WN, wc = w % WN;
    const int l15 = lane & 15, kgrp = lane >> 4;

    // staging map: issue covers 8 super-rows (128B each); lane -> sr+=lane>>3,
    // phys slot lane&7; global content for phys slot s at sr = (s ^ (sr&7)).
    size_t goffA[NA], goffB[NB];
    int ldsoA[NA], ldsoB[NB];
    {
        int s8 = lane & 7, jj = lane >> 3;
#pragma unroll
        for (int i = 0; i < NA; ++i) {
            int sr = (i * WAVES + w) * 8 + jj;
            int x = s8 ^ (sr & 7);
            goffA[i] = (size_t)(bm + sr * 2 + (x >> 2)) * K + (x & 3) * 8;
            ldsoA[i] = (i * WAVES + w) * 512;
        }
#pragma unroll
        for (int i = 0; i < NB; ++i) {
            int sr = (i * WAVES + w) * 8 + jj;
            int x = s8 ^ (sr & 7);
            goffB[i] = (size_t)(bn + sr * 2 + (x >> 2)) * K + (x & 3) * 8;
            ldsoB[i] = (i * WAVES + w) * 512;
        }
    }
    // swizzled ds_read offsets (ushort units)
    int ra[M_REP], rb[4];
#pragma unroll
    for (int m = 0; m < M_REP; ++m) {
        int r = wr * Mw + m * 16 + l15;
        int s8 = (kgrp + 4 * (r & 1)) ^ ((r >> 1) & 7);
        ra[m] = (r >> 1) * 64 + s8 * 8;
    }
#pragma unroll
    for (int n = 0; n < 4; ++n) {
        int r = wc * 64 + n * 16 + l15;
        int s8 = (kgrp + 4 * (r & 1)) ^ ((r >> 1) & 7);
        rb[n] = (r >> 1) * 64 + s8 * 8;
    }

    f32x4 acc[M_REP][4] = {};

#define STAGE(t_, b_) do { size_t k0_ = (size_t)(t_) * 32;             \
    _Pragma("unroll")                                                  \
    for (int i_ = 0; i_ < NA; ++i_)                                    \
        gload_lds16(A + goffA[i_] + k0_, &Asm[b_][ldsoA[i_]]);         \
    _Pragma("unroll")                                                  \
    for (int i_ = 0; i_ < NB; ++i_)                                    \
        gload_lds16(Bt + goffB[i_] + k0_, &Bsm[b_][ldsoB[i_]]); } while (0)

#define WAIT_VM(n_) asm volatile("s_waitcnt vmcnt(" #n_ ")" ::: "memory")

    const int nT = K >> 5;
    STAGE(0, 0); STAGE(1, 1);
    if constexpr (NST == 6) WAIT_VM(6); else if constexpr (NST == 4) WAIT_VM(4); else WAIT_VM(3);
    __builtin_amdgcn_s_barrier();

    int cur = 0;
    for (int tk = 0; tk < nT; ++tk) {
        s16x8 af[M_REP], bfr[4];
#pragma unroll
        for (int m = 0; m < M_REP; ++m)
            af[m] = *reinterpret_cast<const s16x8*>(&Asm[cur][ra[m]]);
#pragma unroll
        for (int n = 0; n < 4; ++n)
            bfr[n] = *reinterpret_cast<const s16x8*>(&Bsm[cur][rb[n]]);
        if (tk + 2 < nT) STAGE(tk + 2, cur == 0 ? 2 : cur - 1);   // (cur+2)%3
        __builtin_amdgcn_s_setprio(1);
#pragma unroll
        for (int m = 0; m < M_REP; ++m)
#pragma unroll
            for (int n = 0; n < 4; ++n)
                acc[m][n] = __builtin_amdgcn_mfma_f32_16x16x32_bf16(af[m], bfr[n], acc[m][n], 0, 0, 0);
        __builtin_amdgcn_s_setprio(0);
        if (tk + 2 < nT) {
            if constexpr (NST == 6) WAIT_VM(6); else if constexpr (NST == 4) WAIT_VM(4); else WAIT_VM(3);
        } else if (tk + 1 < nT) {
            WAIT_VM(0);
        }
        if (tk + 1 < nT) __builtin_amdgcn_s_barrier();
        cur = (cur == 2) ? 0 : cur + 1;
    }
#undef STAGE
#undef WAIT_VM

    // epilogue: C/D layout col = lane&15, row = (lane>>4)*4 + j
    if (EPI == 0) {
#pragma unroll
        for (int m = 0; m < M_REP; ++m) {
            int grow = bm + wr * Mw + m * 16 + kgrp * 4;
#pragma unroll
            for (int n = 0; n < 4; ++n) {
                int gcol = bn + wc * 64 + n * 16 + l15;
                float bb = bias[gcol];
#pragma unroll
                for (int j = 0; j < 4; ++j)
                    C[(size_t)(grow + j) * N + gcol] = acc[m][n][j] + bb;
            }
        }
    } else {
        // wave's 64-col span = one head: softmax over head dim, scale by Vsum
        float bqv[4], ksv[4], vsv[4];
#pragma unroll
        for (int n = 0; n < 4; ++n) {
            int col = bn + wc * 64 + n * 16 + l15;
            bqv[n] = bias[col];
            ksv[n] = kvsum[col];
            vsv[n] = kvsum[HDK + col];
        }
#pragma unroll
        for (int m = 0; m < M_REP; ++m) {
            int grow = bm + wr * Mw + m * 16 + kgrp * 4;
#pragma unroll
            for (int j = 0; j < 4; ++j) {
                float x[4];
#pragma unroll
                for (int n = 0; n < 4; ++n)
                    x[n] = 0.125f * (acc[m][n][j] + bqv[n]) * ksv[n];
                float mx = fmaxf(fmaxf(x[0], x[1]), fmaxf(x[2], x[3]));
#pragma unroll
                for (int off = 8; off; off >>= 1) mx = fmaxf(mx, __shfl_xor(mx, off));
                float e[4], s = 0.f;
#pragma unroll
                for (int n = 0; n < 4; ++n) { e[n] = __expf(x[n] - mx); s += e[n]; }
#pragma unroll
                for (int off = 8; off; off >>= 1) s += __shfl_xor(s, off);
                float inv = 1.0f / s;
#pragma unroll
                for (int n = 0; n < 4; ++n) {
                    int col = bn + wc * 64 + n * 16 + l15;
                    R[(size_t)(grow + j) * N + col] = f2bf(e[n] * inv * vsv[n]);
                }
            }
        }
    }
}

// ---------- host launch ----------
extern "C" void kernel_launch(void* const* d_in, const int* in_sizes, int n_in,
                              void* d_out, int out_size, void* d_ws, size_t ws_size,
                              hipStream_t stream) {
    const float* target = (const float*)d_in[0];
    const float* source = (const float*)d_in[1];
    const float* value  = (const float*)d_in[2];
    const float* Wq = (const float*)d_in[3];
    const float* bq = (const float*)d_in[4];
    const float* Wk = (const float*)d_in[5];
    const float* bk = (const float*)d_in[6];
    const float* Wv = (const float*)d_in[7];
    const float* bv = (const float*)d_in[8];
    const float* Wo = (const float*)d_in[9];
    const float* bo = (const float*)d_in[10];
    float* out = (float*)d_out;

    char* ws = (char*)d_ws;
    float*          part1  = (float*)(ws);                      // 1.25MB
    float*          part2  = (float*)(ws + 0x180000);           // 512KB
    float*          kvsum  = (float*)(ws + 0x210000);           // 8KB
    unsigned short* tgt_bf = (unsigned short*)(ws + 0x400000);  // 8MB
    unsigned short* wq_t   = (unsigned short*)(ws + 0xC00000);  // 2MB
    unsigned short* wo_t   = (unsigned short*)(ws + 0xE00000);  // 8MB
    unsigned short* Rb     = (unsigned short*)(ws + 0x1600000); // 8MB

    // 1) fused prep: colsum partials + cast(target) + transpose(Wq) + transpose(Wo)
    mega1<<<10496, 256, 0, stream>>>(source, value, part1, target, tgt_bf, Wq, wq_t, Wo, wo_t);

    // 2) Ksum/Vsum GEMV + bias fold
    gemv_partial2<<<dim3(4, 64, 2), 256, 0, stream>>>(Wk, Wv, part1, part2);
    gemv_reduce<<<8, 256, 0, stream>>>(part2, bk, bv, kvsum);

    // 3) fused: S = target @ Wq; R = softmax_head(0.125*(S+bq)*Ksum) * Vsum (bf16)
    //    128x64 tiles, 4 waves, grid 512 -> 2 blocks/CU (36KB LDS each)
    gemm_ctd3<1, 128, 64, 4, 1><<<512, 256, 0, stream>>>(
        tgt_bf, wq_t, nullptr, bq, kvsum, Rb, HDK, DMODEL, HDK / 64);

    // 4) out = R @ Wo + bo
    //    256x128 tiles, 4 waves (each 128x64 = m201 wave tile), grid 512
    //    -> 2 independent blocks/CU (72KB LDS each): MFMA of one block
    //    overlaps LDS/staging of the other.
    gemm_ctd3<0, 256, 128, 2, 2><<<512, 256, 0, stream>>>(
        Rb, wo_t, out, bo, nullptr, nullptr, DLLM, HDK, DLLM / 128);
}